// Round 11
// baseline (343.396 us; speedup 1.0000x reference)
//
#include <hip/hip_runtime.h>
#include <math.h>

typedef float f4 __attribute__((ext_vector_type(4)));
typedef float f2 __attribute__((ext_vector_type(2)));

#define NUM_G 64
#define CH 16          // per-graph chunks for deterministic partial reductions
#define EPSV 1e-5f

__device__ inline f4 f4_max(f4 a, f4 b) {
  f4 r;
#pragma unroll
  for (int i = 0; i < 4; ++i) r[i] = fmaxf(a[i], b[i]);
  return r;
}

// ---------------- init: deg=1 (self loop), ecnt=0, graph start offsets ----------------
__global__ void k_init(const int* __restrict__ batch, float* __restrict__ deg,
                       int* __restrict__ ecnt, int* __restrict__ gstart, int N) {
  int n = blockIdx.x * blockDim.x + threadIdx.x;
  if (n >= N) return;
  deg[n] = 1.0f;
  ecnt[n] = 0;
  int bn = batch[n];
  int bp = (n == 0) ? -1 : batch[n - 1];
  for (int g = bp + 1; g <= bn; ++g) gstart[g] = n;
  if (n == N - 1) {
    for (int g = bn + 1; g <= NUM_G; ++g) gstart[g] = N;
  }
}

// ---------------- weighted in-degree + edge count histogram ----------------
__global__ void k_deg(const int* __restrict__ col, const float* __restrict__ ew,
                      float* __restrict__ deg, int* __restrict__ ecnt, int E) {
  int e = blockIdx.x * blockDim.x + threadIdx.x;
  if (e >= E) return;
  int c = col[e];
  atomicAdd(&deg[c], ew[e]);
  atomicAdd(&ecnt[c], 1);
}

// ---------------- two-level scan, phase A: per-block totals ----------------
__global__ __launch_bounds__(256) void k_scanA(const int* __restrict__ ecnt,
                                               int* __restrict__ bsum, int N) {
  __shared__ int sb[256];
  int n = blockIdx.x * 256 + threadIdx.x;
  sb[threadIdx.x] = (n < N) ? ecnt[n] : 0;
  __syncthreads();
  for (int o = 128; o >= 1; o >>= 1) {
    if (threadIdx.x < o) sb[threadIdx.x] += sb[threadIdx.x + o];
    __syncthreads();
  }
  if (threadIdx.x == 0) bsum[blockIdx.x] = sb[0];
}

// ---------------- phase B: scan the block sums (single small block) ----------------
__global__ __launch_bounds__(1024) void k_scanB(int* __restrict__ bsum,
                                                int* __restrict__ off, int NB, int N) {
  __shared__ int sb[1024];
  int t = threadIdx.x;
  int sc = (NB + 1023) >> 10;  // entries per thread (1 for NB<=1024)
  int s = t * sc, e = min(s + sc, NB);
  int local = 0;
  for (int i = s; i < e; ++i) local += bsum[i];
  sb[t] = local;
  __syncthreads();
  for (int o = 1; o < 1024; o <<= 1) {
    int v = sb[t];
    int a = (t >= o) ? sb[t - o] : 0;
    __syncthreads();
    sb[t] = v + a;
    __syncthreads();
  }
  int running = sb[t] - local;  // exclusive base for this thread's span
  for (int i = s; i < e; ++i) {
    int v = bsum[i];
    bsum[i] = running;
    running += v;
  }
  if (t == 0) off[N] = sb[1023];  // grand total
}

// ---------------- phase C: intra-block scan + base -> off/cursor; dis = rsqrt(deg) ----------------
__global__ __launch_bounds__(256) void k_scanC(const int* __restrict__ ecnt,
                                               const int* __restrict__ bsum,
                                               const float* __restrict__ deg,
                                               int* __restrict__ off, int* __restrict__ cursor,
                                               float* __restrict__ dis, int N) {
  __shared__ int sb[256];
  int n = blockIdx.x * 256 + threadIdx.x;
  int v = (n < N) ? ecnt[n] : 0;
  sb[threadIdx.x] = v;
  __syncthreads();
  for (int o = 1; o < 256; o <<= 1) {
    int x = sb[threadIdx.x];
    int a = (threadIdx.x >= o) ? sb[threadIdx.x - o] : 0;
    __syncthreads();
    sb[threadIdx.x] = x + a;
    __syncthreads();
  }
  if (n < N) {
    int ex = bsum[blockIdx.x] + sb[threadIdx.x] - v;  // exclusive prefix
    off[n] = ex;
    cursor[n] = ex;
    float d = deg[n];
    dis[n] = (d > 0.f) ? (1.0f / sqrtf(d)) : 0.f;
  }
}

// ---------------- GEMM: x = inputs @ W, both tiles LDS-staged (coalesced A!) ----------------
// BM=64, BK=32, BN=128. 512 threads: lane=tid&31 -> 4 cols, rg=tid>>5 (0..15) -> 4 rows.
__global__ __launch_bounds__(512) void k_gemm(const float* __restrict__ in,
                                              const float* __restrict__ Wg,
                                              float* __restrict__ x, int N) {
  __shared__ float As[64][32];   // 8 KiB
  __shared__ float Ws[32][128];  // 16 KiB
  int tid = threadIdx.x;
  int lane = tid & 31;   // cols 4*lane..4*lane+3
  int rg = tid >> 5;     // rows rg*4..rg*4+3
  int brow = blockIdx.x * 64;
  int ar = tid >> 3;         // 0..63: A stage row
  int aseg = (tid & 7) * 4;  // float offset within 32-float chunk
  const f4* wsrc0 = (const f4*)Wg;
  f4 acc0 = (f4)0.f, acc1 = (f4)0.f, acc2 = (f4)0.f, acc3 = (f4)0.f;
  for (int kc = 0; kc < 4; ++kc) {  // K chunks of 32, ascending (same summation order)
    int gr = brow + ar;
    f4 av = (f4)0.f;
    if (gr < N) av = *(const f4*)(in + (size_t)gr * 128 + kc * 32 + aseg);
    *(f4*)&As[ar][aseg] = av;
    const f4* wsrc = wsrc0 + (size_t)kc * 32 * 32;  // kc*32 rows, 32 f4 per row
    ((f4*)Ws)[tid] = wsrc[tid];
    ((f4*)Ws)[tid + 512] = wsrc[tid + 512];
    __syncthreads();
#pragma unroll
    for (int k4 = 0; k4 < 8; ++k4) {
      f4 a0 = *(const f4*)&As[rg * 4 + 0][k4 * 4];
      f4 a1 = *(const f4*)&As[rg * 4 + 1][k4 * 4];
      f4 a2 = *(const f4*)&As[rg * 4 + 2][k4 * 4];
      f4 a3 = *(const f4*)&As[rg * 4 + 3][k4 * 4];
#pragma unroll
      for (int kk = 0; kk < 4; ++kk) {
        f4 wv = *(const f4*)&Ws[k4 * 4 + kk][lane * 4];
        acc0 += a0[kk] * wv;
        acc1 += a1[kk] * wv;
        acc2 += a2[kk] * wv;
        acc3 += a3[kk] * wv;
      }
    }
    __syncthreads();
  }
  int r0 = brow + rg * 4;
  if (r0 + 0 < N) ((f4*)(x + (size_t)(r0 + 0) * 128))[lane] = acc0;
  if (r0 + 1 < N) ((f4*)(x + (size_t)(r0 + 1) * 128))[lane] = acc1;
  if (r0 + 2 < N) ((f4*)(x + (size_t)(r0 + 2) * 128))[lane] = acc2;
  if (r0 + 3 < N) ((f4*)(x + (size_t)(r0 + 3) * 128))[lane] = acc3;
}

// ---------------- counting-sort scatter: build CSR-by-target (srow, snorm) ----------------
__global__ void k_scatter(const int* __restrict__ row, const int* __restrict__ col,
                          const float* __restrict__ ew, const float* __restrict__ dis,
                          int* __restrict__ cursor, int* __restrict__ srow,
                          float* __restrict__ snorm, int E) {
  int e = blockIdx.x * blockDim.x + threadIdx.x;
  if (e >= E) return;
  int r = row[e], c = col[e];
  float nm = dis[r] * ew[e] * dis[c];
  int p = atomicAdd(&cursor[c], 1);
  srow[p] = r;
  snorm[p] = nm;
}

// ---------------- per-node gather-accumulate: out = sum(msg) + selfloop + bias ----------------
// one node per 64-lane wave (f2/lane = 128 feats); 4 waves (nodes) per block.
// Mean degree ~6: the old 4-wide loop + serial remainder left 1-2 singleton gathers
// exposed at full memory latency. Now: predicated 8-wide batches (clamped index, zero
// norm for pads) so a typical node's ENTIRE gather set issues in one overlapped batch.
__global__ __launch_bounds__(256) void k_accum(const float* __restrict__ x,
                                               const float* __restrict__ dis,
                                               const int* __restrict__ off,
                                               const int* __restrict__ srow,
                                               const float* __restrict__ snorm,
                                               const float* __restrict__ bias,
                                               float* __restrict__ out, int N) {
  int lane = threadIdx.x & 63;  // 64 lanes x float2 = 128 features
  int sub = threadIdx.x >> 6;   // 4 nodes per block
  int n = blockIdx.x * 4 + sub;
  if (n >= N) return;
  const f2* x2 = (const f2*)x;
  float dn = dis[n];
  f2 a0 = x2[(size_t)n * 64 + lane] * (dn * dn);  // self-loop: norm = dis[n]^2
  f2 a1 = (f2)0.f, a2 = (f2)0.f, a3 = (f2)0.f;
  f2 a4 = (f2)0.f, a5 = (f2)0.f, a6 = (f2)0.f, a7 = (f2)0.f;
  int s = off[n], e = off[n + 1];
  for (int i = s; i < e; i += 8) {
    int e1 = e - 1;
    int i1 = min(i + 1, e1), i2 = min(i + 2, e1), i3 = min(i + 3, e1);
    int i4 = min(i + 4, e1), i5 = min(i + 5, e1), i6 = min(i + 6, e1), i7 = min(i + 7, e1);
    int r0 = srow[i],  r1 = srow[i1], r2 = srow[i2], r3 = srow[i3];
    int r4 = srow[i4], r5 = srow[i5], r6 = srow[i6], r7 = srow[i7];
    float n0 = snorm[i];
    float n1 = (i + 1 < e) ? snorm[i1] : 0.f;
    float n2 = (i + 2 < e) ? snorm[i2] : 0.f;
    float n3 = (i + 3 < e) ? snorm[i3] : 0.f;
    float n4 = (i + 4 < e) ? snorm[i4] : 0.f;
    float n5 = (i + 5 < e) ? snorm[i5] : 0.f;
    float n6 = (i + 6 < e) ? snorm[i6] : 0.f;
    float n7 = (i + 7 < e) ? snorm[i7] : 0.f;
    a0 += x2[(size_t)r0 * 64 + lane] * n0;
    a1 += x2[(size_t)r1 * 64 + lane] * n1;
    a2 += x2[(size_t)r2 * 64 + lane] * n2;
    a3 += x2[(size_t)r3 * 64 + lane] * n3;
    a4 += x2[(size_t)r4 * 64 + lane] * n4;
    a5 += x2[(size_t)r5 * 64 + lane] * n5;
    a6 += x2[(size_t)r6 * 64 + lane] * n6;
    a7 += x2[(size_t)r7 * 64 + lane] * n7;
  }
  f2 acc = ((a0 + a1) + (a2 + a3)) + ((a4 + a5) + (a6 + a7)) + ((const f2*)bias)[lane];
  ((f2*)out)[(size_t)n * 64 + lane] = acc;
}

// ---------------- GraphNorm fused stats: partial sum AND sum-of-squares per (graph, chunk) ----------------
__global__ __launch_bounds__(256) void k_stats(const float* __restrict__ out,
                                               const int* __restrict__ gstart,
                                               float* __restrict__ Ssum,
                                               float* __restrict__ Ssq) {
  int g = blockIdx.x / CH, c = blockIdx.x % CH;
  int s = gstart[g], e = gstart[g + 1];
  int len = e - s;
  int csz = (len + CH - 1) / CH;
  int r0 = s + c * csz, r1 = min(r0 + csz, e);
  int lane = threadIdx.x & 31, rg = threadIdx.x >> 5;
  const f4* out4 = (const f4*)out;
  f4 acc = (f4)0.f, accq = (f4)0.f;
  for (int r = r0 + rg; r < r1; r += 8) {
    f4 v = out4[(size_t)r * 32 + lane];
    acc += v;
    accq += v * v;
  }
  __shared__ f4 red[256], redq[256];
  red[threadIdx.x] = acc;
  redq[threadIdx.x] = accq;
  __syncthreads();
  for (int st = 4; st >= 1; st >>= 1) {
    if (rg < st) {
      red[threadIdx.x] += red[threadIdx.x + st * 32];
      redq[threadIdx.x] += redq[threadIdx.x + st * 32];
    }
    __syncthreads();
  }
  if (rg == 0) {
    ((f4*)Ssum)[(size_t)(g * CH + c) * 32 + lane] = red[threadIdx.x];
    ((f4*)Ssq)[(size_t)(g * CH + c) * 32 + lane] = redq[threadIdx.x];
  }
}

// ---------------- finalize: h = relu((out-alpha*mean)*invstd*w + b); partial max ----------------
// var = E[(out-am)^2] = E[out^2] - 2*am*E[out] + am^2, am = alpha*mean
__global__ __launch_bounds__(256) void k_final(float* __restrict__ out,
                                               const int* __restrict__ gstart,
                                               const float* __restrict__ Ssum,
                                               const float* __restrict__ Ssq,
                                               const float* __restrict__ alpha,
                                               const float* __restrict__ gw,
                                               const float* __restrict__ gb,
                                               float* __restrict__ Pmax) {
  int g = blockIdx.x / CH, c = blockIdx.x % CH;
  int s = gstart[g], e = gstart[g + 1];
  int len = e - s;
  float inv_cnt = 1.0f / (float)((len < 1) ? 1 : len);
  __shared__ f4 aml[32], istdl[32];
  int lane = threadIdx.x & 31, rg = threadIdx.x >> 5;
  if (threadIdx.x < 32) {
    f4 m = (f4)0.f, q = (f4)0.f;
    for (int cc = 0; cc < CH; ++cc) {
      m += ((const f4*)Ssum)[(size_t)(g * CH + cc) * 32 + threadIdx.x];
      q += ((const f4*)Ssq)[(size_t)(g * CH + cc) * 32 + threadIdx.x];
    }
    m *= inv_cnt;                                 // E[out]
    q *= inv_cnt;                                 // E[out^2]
    f4 al = ((const f4*)alpha)[threadIdx.x];
    f4 am = al * m;
    f4 var = q - 2.0f * am * m + am * am;         // E[(out-am)^2]
    f4 is;
#pragma unroll
    for (int i = 0; i < 4; ++i) is[i] = 1.0f / sqrtf(var[i] + EPSV);
    aml[threadIdx.x] = am;
    istdl[threadIdx.x] = is;
  }
  __syncthreads();
  int csz = (len + CH - 1) / CH;
  int r0 = s + c * csz, r1 = min(r0 + csz, e);
  f4 am = aml[lane];
  f4 is = istdl[lane];
  f4 w4 = ((const f4*)gw)[lane];
  f4 b4 = ((const f4*)gb)[lane];
  f4* out4 = (f4*)out;
  f4 mx = (f4)0.f;  // relu output >= 0, so 0 is a safe identity
  for (int r = r0 + rg; r < r1; r += 8) {
    f4 o = out4[(size_t)r * 32 + lane];
    f4 h = (o - am) * is * w4 + b4;
    h = f4_max(h, (f4)0.f);
    out4[(size_t)r * 32 + lane] = h;
    mx = f4_max(mx, h);
  }
  __shared__ f4 red[256];
  red[threadIdx.x] = mx;
  __syncthreads();
  for (int st = 4; st >= 1; st >>= 1) {
    if (rg < st) red[threadIdx.x] = f4_max(red[threadIdx.x], red[threadIdx.x + st * 32]);
    __syncthreads();
  }
  if (rg == 0) ((f4*)Pmax)[(size_t)(g * CH + c) * 32 + lane] = red[threadIdx.x];
}

// ---------------- combine partial maxes -> flat ----------------
__global__ void k_flat(const float* __restrict__ Pmax, float* __restrict__ flat) {
  int g = blockIdx.x;
  int f = threadIdx.x;  // 128 threads
  float m = 0.f;
  for (int c = 0; c < CH; ++c) m = fmaxf(m, Pmax[((size_t)g * CH + c) * 128 + f]);
  flat[g * 128 + f] = m;
}

extern "C" void kernel_launch(void* const* d_in, const int* in_sizes, int n_in,
                              void* d_out, int out_size, void* d_ws, size_t ws_size,
                              hipStream_t stream) {
  const float* inputs = (const float*)d_in[0];
  const int* eidx = (const int*)d_in[1];
  const int* batch = (const int*)d_in[2];
  const float* ew = (const float*)d_in[3];
  const float* Wg = (const float*)d_in[4];
  const float* bias = (const float*)d_in[5];
  const float* gw = (const float*)d_in[6];
  const float* gb = (const float*)d_in[7];
  const float* galpha = (const float*)d_in[8];

  int N = in_sizes[0] / 128;
  int E = in_sizes[1] / 2;
  const int* erow = eidx;       // edge_index[0] = source
  const int* ecol = eidx + E;   // edge_index[1] = target

  char* w = (char*)d_ws;
  auto alloc = [&](size_t bytes) {
    char* p = w;
    w += (bytes + 255) & ~(size_t)255;
    return p;
  };
  float* x = (float*)alloc((size_t)N * 128 * 4);
  float* deg = (float*)alloc((size_t)N * 4);
  float* dis = (float*)alloc((size_t)N * 4);
  int* ecnt = (int*)alloc((size_t)N * 4);
  int* off = (int*)alloc((size_t)(N + 1) * 4);
  int* cursor = (int*)alloc((size_t)N * 4);
  int* srow = (int*)alloc((size_t)E * 4);
  float* snorm = (float*)alloc((size_t)E * 4);
  int* gstart = (int*)alloc((size_t)(NUM_G + 1) * 4);
  float* Ssum = (float*)alloc((size_t)NUM_G * CH * 128 * 4);
  float* Ssq = (float*)alloc((size_t)NUM_G * CH * 128 * 4);
  float* Pmax = (float*)alloc((size_t)NUM_G * CH * 128 * 4);
  int NB = (N + 255) / 256;
  int* bsum = (int*)alloc((size_t)NB * 4);

  float* outh = (float*)d_out;             // h: N x 128
  float* flat = outh + (size_t)N * 128;    // flat: 64 x 128

  k_init<<<(N + 255) / 256, 256, 0, stream>>>(batch, deg, ecnt, gstart, N);
  k_deg<<<(E + 255) / 256, 256, 0, stream>>>(ecol, ew, deg, ecnt, E);
  k_scanA<<<NB, 256, 0, stream>>>(ecnt, bsum, N);
  k_scanB<<<1, 1024, 0, stream>>>(bsum, off, NB, N);
  k_scanC<<<NB, 256, 0, stream>>>(ecnt, bsum, deg, off, cursor, dis, N);
  k_gemm<<<(N + 63) / 64, 512, 0, stream>>>(inputs, Wg, x, N);
  k_scatter<<<(E + 255) / 256, 256, 0, stream>>>(erow, ecol, ew, dis, cursor, srow, snorm, E);
  k_accum<<<(N + 3) / 4, 256, 0, stream>>>(x, dis, off, srow, snorm, bias, outh, N);
  k_stats<<<NUM_G * CH, 256, 0, stream>>>(outh, gstart, Ssum, Ssq);
  k_final<<<NUM_G * CH, 256, 0, stream>>>(outh, gstart, Ssum, Ssq, galpha, gw, gb, Pmax);
  k_flat<<<NUM_G, 128, 0, stream>>>(Pmax, flat);
}

// Round 14
// 332.300 us; speedup vs baseline: 1.0334x; 1.0334x over previous
//
#include <hip/hip_runtime.h>
#include <math.h>

typedef float f4 __attribute__((ext_vector_type(4)));
typedef float f2 __attribute__((ext_vector_type(2)));

#define NUM_G 64
#define CH 16          // per-graph chunks for deterministic partial reductions
#define EPSV 1e-5f

__device__ inline f4 f4_max(f4 a, f4 b) {
  f4 r;
#pragma unroll
  for (int i = 0; i < 4; ++i) r[i] = fmaxf(a[i], b[i]);
  return r;
}

// ---------------- init: deg=1 (self loop), ecnt=0, graph start offsets ----------------
__global__ void k_init(const int* __restrict__ batch, float* __restrict__ deg,
                       int* __restrict__ ecnt, int* __restrict__ gstart, int N) {
  int n = blockIdx.x * blockDim.x + threadIdx.x;
  if (n >= N) return;
  deg[n] = 1.0f;
  ecnt[n] = 0;
  int bn = batch[n];
  int bp = (n == 0) ? -1 : batch[n - 1];
  for (int g = bp + 1; g <= bn; ++g) gstart[g] = n;
  if (n == N - 1) {
    for (int g = bn + 1; g <= NUM_G; ++g) gstart[g] = N;
  }
}

// ---------------- weighted in-degree + edge count histogram ----------------
__global__ void k_deg(const int* __restrict__ col, const float* __restrict__ ew,
                      float* __restrict__ deg, int* __restrict__ ecnt, int E) {
  int e = blockIdx.x * blockDim.x + threadIdx.x;
  if (e >= E) return;
  int c = col[e];
  atomicAdd(&deg[c], ew[e]);
  atomicAdd(&ecnt[c], 1);
}

// ---------------- two-level scan, phase A: per-block totals ----------------
__global__ __launch_bounds__(256) void k_scanA(const int* __restrict__ ecnt,
                                               int* __restrict__ bsum, int N) {
  __shared__ int sb[256];
  int n = blockIdx.x * 256 + threadIdx.x;
  sb[threadIdx.x] = (n < N) ? ecnt[n] : 0;
  __syncthreads();
  for (int o = 128; o >= 1; o >>= 1) {
    if (threadIdx.x < o) sb[threadIdx.x] += sb[threadIdx.x + o];
    __syncthreads();
  }
  if (threadIdx.x == 0) bsum[blockIdx.x] = sb[0];
}

// ---------------- phase B: scan the block sums (single small block) ----------------
__global__ __launch_bounds__(1024) void k_scanB(int* __restrict__ bsum,
                                                int* __restrict__ off, int NB, int N) {
  __shared__ int sb[1024];
  int t = threadIdx.x;
  int sc = (NB + 1023) >> 10;  // entries per thread (1 for NB<=1024)
  int s = t * sc, e = min(s + sc, NB);
  int local = 0;
  for (int i = s; i < e; ++i) local += bsum[i];
  sb[t] = local;
  __syncthreads();
  for (int o = 1; o < 1024; o <<= 1) {
    int v = sb[t];
    int a = (t >= o) ? sb[t - o] : 0;
    __syncthreads();
    sb[t] = v + a;
    __syncthreads();
  }
  int running = sb[t] - local;  // exclusive base for this thread's span
  for (int i = s; i < e; ++i) {
    int v = bsum[i];
    bsum[i] = running;
    running += v;
  }
  if (t == 0) off[N] = sb[1023];  // grand total
}

// ---------------- phase C: intra-block scan + base -> off/cursor; dis = rsqrt(deg) ----------------
__global__ __launch_bounds__(256) void k_scanC(const int* __restrict__ ecnt,
                                               const int* __restrict__ bsum,
                                               const float* __restrict__ deg,
                                               int* __restrict__ off, int* __restrict__ cursor,
                                               float* __restrict__ dis, int N) {
  __shared__ int sb[256];
  int n = blockIdx.x * 256 + threadIdx.x;
  int v = (n < N) ? ecnt[n] : 0;
  sb[threadIdx.x] = v;
  __syncthreads();
  for (int o = 1; o < 256; o <<= 1) {
    int x = sb[threadIdx.x];
    int a = (threadIdx.x >= o) ? sb[threadIdx.x - o] : 0;
    __syncthreads();
    sb[threadIdx.x] = x + a;
    __syncthreads();
  }
  if (n < N) {
    int ex = bsum[blockIdx.x] + sb[threadIdx.x] - v;  // exclusive prefix
    off[n] = ex;
    cursor[n] = ex;
    float d = deg[n];
    dis[n] = (d > 0.f) ? (1.0f / sqrtf(d)) : 0.f;
  }
}

// ---------------- GEMM: x = inputs @ W, both tiles LDS-staged (coalesced A!) ----------------
// BM=64, BK=32, BN=128. 512 threads: lane=tid&31 -> 4 cols, rg=tid>>5 (0..15) -> 4 rows.
__global__ __launch_bounds__(512) void k_gemm(const float* __restrict__ in,
                                              const float* __restrict__ Wg,
                                              float* __restrict__ x, int N) {
  __shared__ float As[64][32];   // 8 KiB
  __shared__ float Ws[32][128];  // 16 KiB
  int tid = threadIdx.x;
  int lane = tid & 31;   // cols 4*lane..4*lane+3
  int rg = tid >> 5;     // rows rg*4..rg*4+3
  int brow = blockIdx.x * 64;
  int ar = tid >> 3;         // 0..63: A stage row
  int aseg = (tid & 7) * 4;  // float offset within 32-float chunk
  const f4* wsrc0 = (const f4*)Wg;
  f4 acc0 = (f4)0.f, acc1 = (f4)0.f, acc2 = (f4)0.f, acc3 = (f4)0.f;
  for (int kc = 0; kc < 4; ++kc) {  // K chunks of 32, ascending (same summation order)
    int gr = brow + ar;
    f4 av = (f4)0.f;
    if (gr < N) av = *(const f4*)(in + (size_t)gr * 128 + kc * 32 + aseg);
    *(f4*)&As[ar][aseg] = av;
    const f4* wsrc = wsrc0 + (size_t)kc * 32 * 32;  // kc*32 rows, 32 f4 per row
    ((f4*)Ws)[tid] = wsrc[tid];
    ((f4*)Ws)[tid + 512] = wsrc[tid + 512];
    __syncthreads();
#pragma unroll
    for (int k4 = 0; k4 < 8; ++k4) {
      f4 a0 = *(const f4*)&As[rg * 4 + 0][k4 * 4];
      f4 a1 = *(const f4*)&As[rg * 4 + 1][k4 * 4];
      f4 a2 = *(const f4*)&As[rg * 4 + 2][k4 * 4];
      f4 a3 = *(const f4*)&As[rg * 4 + 3][k4 * 4];
#pragma unroll
      for (int kk = 0; kk < 4; ++kk) {
        f4 wv = *(const f4*)&Ws[k4 * 4 + kk][lane * 4];
        acc0 += a0[kk] * wv;
        acc1 += a1[kk] * wv;
        acc2 += a2[kk] * wv;
        acc3 += a3[kk] * wv;
      }
    }
    __syncthreads();
  }
  int r0 = brow + rg * 4;
  if (r0 + 0 < N) ((f4*)(x + (size_t)(r0 + 0) * 128))[lane] = acc0;
  if (r0 + 1 < N) ((f4*)(x + (size_t)(r0 + 1) * 128))[lane] = acc1;
  if (r0 + 2 < N) ((f4*)(x + (size_t)(r0 + 2) * 128))[lane] = acc2;
  if (r0 + 3 < N) ((f4*)(x + (size_t)(r0 + 3) * 128))[lane] = acc3;
}

// ---------------- counting-sort scatter: build CSR-by-target, PACKED (r, norm) ----------------
// One 8B scattered store per edge instead of two 4B stores to separate arrays:
// halves scattered-write transactions and L2 line touches.
__global__ void k_scatter(const int* __restrict__ row, const int* __restrict__ col,
                          const float* __restrict__ ew, const float* __restrict__ dis,
                          int* __restrict__ cursor, int2* __restrict__ sdata, int E) {
  int e = blockIdx.x * blockDim.x + threadIdx.x;
  if (e >= E) return;
  int r = row[e], c = col[e];
  float nm = dis[r] * ew[e] * dis[c];
  int p = atomicAdd(&cursor[c], 1);
  int2 pk;
  pk.x = r;
  pk.y = __float_as_int(nm);
  sdata[p] = pk;
}

// ---------------- per-node gather-accumulate: out = sum(msg) + selfloop + bias ----------------
// one node per 64-lane wave (f2/lane = 128 feats); 4 waves (nodes) per block.
// Round-10 structure (4-wide + remainder; 8-wide predicated batching regressed: +33%
// memory instrs from pads, +14pt VALUBusy, -14pt occupancy). CSR payload now packed int2.
__global__ __launch_bounds__(256) void k_accum(const float* __restrict__ x,
                                               const float* __restrict__ dis,
                                               const int* __restrict__ off,
                                               const int2* __restrict__ sdata,
                                               const float* __restrict__ bias,
                                               float* __restrict__ out, int N) {
  int lane = threadIdx.x & 63;  // 64 lanes x float2 = 128 features
  int sub = threadIdx.x >> 6;   // 4 nodes per block
  int n = blockIdx.x * 4 + sub;
  if (n >= N) return;
  const f2* x2 = (const f2*)x;
  float dn = dis[n];
  f2 acc0 = x2[(size_t)n * 64 + lane] * (dn * dn);  // self-loop: norm = dis[n]^2
  f2 acc1 = (f2)0.f, acc2 = (f2)0.f, acc3 = (f2)0.f;
  int s = off[n], e = off[n + 1];
  int i = s;
  for (; i + 4 <= e; i += 4) {  // 4-deep MLP on the random row gathers
    int2 p0 = sdata[i], p1 = sdata[i + 1], p2 = sdata[i + 2], p3 = sdata[i + 3];
    acc0 += x2[(size_t)p0.x * 64 + lane] * __int_as_float(p0.y);
    acc1 += x2[(size_t)p1.x * 64 + lane] * __int_as_float(p1.y);
    acc2 += x2[(size_t)p2.x * 64 + lane] * __int_as_float(p2.y);
    acc3 += x2[(size_t)p3.x * 64 + lane] * __int_as_float(p3.y);
  }
  for (; i < e; ++i) {
    int2 p = sdata[i];
    acc0 += x2[(size_t)p.x * 64 + lane] * __int_as_float(p.y);
  }
  acc0 += (acc1 + acc2) + (acc3 + ((const f2*)bias)[lane]);
  ((f2*)out)[(size_t)n * 64 + lane] = acc0;
}

// ---------------- GraphNorm fused stats: partial sum AND sum-of-squares per (graph, chunk) ----------------
__global__ __launch_bounds__(256) void k_stats(const float* __restrict__ out,
                                               const int* __restrict__ gstart,
                                               float* __restrict__ Ssum,
                                               float* __restrict__ Ssq) {
  int g = blockIdx.x / CH, c = blockIdx.x % CH;
  int s = gstart[g], e = gstart[g + 1];
  int len = e - s;
  int csz = (len + CH - 1) / CH;
  int r0 = s + c * csz, r1 = min(r0 + csz, e);
  int lane = threadIdx.x & 31, rg = threadIdx.x >> 5;
  const f4* out4 = (const f4*)out;
  f4 acc = (f4)0.f, accq = (f4)0.f;
  for (int r = r0 + rg; r < r1; r += 8) {
    f4 v = out4[(size_t)r * 32 + lane];
    acc += v;
    accq += v * v;
  }
  __shared__ f4 red[256], redq[256];
  red[threadIdx.x] = acc;
  redq[threadIdx.x] = accq;
  __syncthreads();
  for (int st = 4; st >= 1; st >>= 1) {
    if (rg < st) {
      red[threadIdx.x] += red[threadIdx.x + st * 32];
      redq[threadIdx.x] += redq[threadIdx.x + st * 32];
    }
    __syncthreads();
  }
  if (rg == 0) {
    ((f4*)Ssum)[(size_t)(g * CH + c) * 32 + lane] = red[threadIdx.x];
    ((f4*)Ssq)[(size_t)(g * CH + c) * 32 + lane] = redq[threadIdx.x];
  }
}

// ---------------- finalize: h = relu((out-alpha*mean)*invstd*w + b); partial max ----------------
// var = E[(out-am)^2] = E[out^2] - 2*am*E[out] + am^2, am = alpha*mean
__global__ __launch_bounds__(256) void k_final(float* __restrict__ out,
                                               const int* __restrict__ gstart,
                                               const float* __restrict__ Ssum,
                                               const float* __restrict__ Ssq,
                                               const float* __restrict__ alpha,
                                               const float* __restrict__ gw,
                                               const float* __restrict__ gb,
                                               float* __restrict__ Pmax) {
  int g = blockIdx.x / CH, c = blockIdx.x % CH;
  int s = gstart[g], e = gstart[g + 1];
  int len = e - s;
  float inv_cnt = 1.0f / (float)((len < 1) ? 1 : len);
  __shared__ f4 aml[32], istdl[32];
  int lane = threadIdx.x & 31, rg = threadIdx.x >> 5;
  if (threadIdx.x < 32) {
    f4 m = (f4)0.f, q = (f4)0.f;
    for (int cc = 0; cc < CH; ++cc) {
      m += ((const f4*)Ssum)[(size_t)(g * CH + cc) * 32 + threadIdx.x];
      q += ((const f4*)Ssq)[(size_t)(g * CH + cc) * 32 + threadIdx.x];
    }
    m *= inv_cnt;                                 // E[out]
    q *= inv_cnt;                                 // E[out^2]
    f4 al = ((const f4*)alpha)[threadIdx.x];
    f4 am = al * m;
    f4 var = q - 2.0f * am * m + am * am;         // E[(out-am)^2]
    f4 is;
#pragma unroll
    for (int i = 0; i < 4; ++i) is[i] = 1.0f / sqrtf(var[i] + EPSV);
    aml[threadIdx.x] = am;
    istdl[threadIdx.x] = is;
  }
  __syncthreads();
  int csz = (len + CH - 1) / CH;
  int r0 = s + c * csz, r1 = min(r0 + csz, e);
  f4 am = aml[lane];
  f4 is = istdl[lane];
  f4 w4 = ((const f4*)gw)[lane];
  f4 b4 = ((const f4*)gb)[lane];
  f4* out4 = (f4*)out;
  f4 mx = (f4)0.f;  // relu output >= 0, so 0 is a safe identity
  for (int r = r0 + rg; r < r1; r += 8) {
    f4 o = out4[(size_t)r * 32 + lane];
    f4 h = (o - am) * is * w4 + b4;
    h = f4_max(h, (f4)0.f);
    out4[(size_t)r * 32 + lane] = h;
    mx = f4_max(mx, h);
  }
  __shared__ f4 red[256];
  red[threadIdx.x] = mx;
  __syncthreads();
  for (int st = 4; st >= 1; st >>= 1) {
    if (rg < st) red[threadIdx.x] = f4_max(red[threadIdx.x], red[threadIdx.x + st * 32]);
    __syncthreads();
  }
  if (rg == 0) ((f4*)Pmax)[(size_t)(g * CH + c) * 32 + lane] = red[threadIdx.x];
}

// ---------------- combine partial maxes -> flat ----------------
__global__ void k_flat(const float* __restrict__ Pmax, float* __restrict__ flat) {
  int g = blockIdx.x;
  int f = threadIdx.x;  // 128 threads
  float m = 0.f;
  for (int c = 0; c < CH; ++c) m = fmaxf(m, Pmax[((size_t)g * CH + c) * 128 + f]);
  flat[g * 128 + f] = m;
}

extern "C" void kernel_launch(void* const* d_in, const int* in_sizes, int n_in,
                              void* d_out, int out_size, void* d_ws, size_t ws_size,
                              hipStream_t stream) {
  const float* inputs = (const float*)d_in[0];
  const int* eidx = (const int*)d_in[1];
  const int* batch = (const int*)d_in[2];
  const float* ew = (const float*)d_in[3];
  const float* Wg = (const float*)d_in[4];
  const float* bias = (const float*)d_in[5];
  const float* gw = (const float*)d_in[6];
  const float* gb = (const float*)d_in[7];
  const float* galpha = (const float*)d_in[8];

  int N = in_sizes[0] / 128;
  int E = in_sizes[1] / 2;
  const int* erow = eidx;       // edge_index[0] = source
  const int* ecol = eidx + E;   // edge_index[1] = target

  char* w = (char*)d_ws;
  auto alloc = [&](size_t bytes) {
    char* p = w;
    w += (bytes + 255) & ~(size_t)255;
    return p;
  };
  float* x = (float*)alloc((size_t)N * 128 * 4);
  float* deg = (float*)alloc((size_t)N * 4);
  float* dis = (float*)alloc((size_t)N * 4);
  int* ecnt = (int*)alloc((size_t)N * 4);
  int* off = (int*)alloc((size_t)(N + 1) * 4);
  int* cursor = (int*)alloc((size_t)N * 4);
  int2* sdata = (int2*)alloc((size_t)E * 8);
  int* gstart = (int*)alloc((size_t)(NUM_G + 1) * 4);
  float* Ssum = (float*)alloc((size_t)NUM_G * CH * 128 * 4);
  float* Ssq = (float*)alloc((size_t)NUM_G * CH * 128 * 4);
  float* Pmax = (float*)alloc((size_t)NUM_G * CH * 128 * 4);
  int NB = (N + 255) / 256;
  int* bsum = (int*)alloc((size_t)NB * 4);

  float* outh = (float*)d_out;             // h: N x 128
  float* flat = outh + (size_t)N * 128;    // flat: 64 x 128

  k_init<<<(N + 255) / 256, 256, 0, stream>>>(batch, deg, ecnt, gstart, N);
  k_deg<<<(E + 255) / 256, 256, 0, stream>>>(ecol, ew, deg, ecnt, E);
  k_scanA<<<NB, 256, 0, stream>>>(ecnt, bsum, N);
  k_scanB<<<1, 1024, 0, stream>>>(bsum, off, NB, N);
  k_scanC<<<NB, 256, 0, stream>>>(ecnt, bsum, deg, off, cursor, dis, N);
  k_gemm<<<(N + 63) / 64, 512, 0, stream>>>(inputs, Wg, x, N);
  k_scatter<<<(E + 255) / 256, 256, 0, stream>>>(erow, ecol, ew, dis, cursor, sdata, E);
  k_accum<<<(N + 3) / 4, 256, 0, stream>>>(x, dis, off, sdata, bias, outh, N);
  k_stats<<<NUM_G * CH, 256, 0, stream>>>(outh, gstart, Ssum, Ssq);
  k_final<<<NUM_G * CH, 256, 0, stream>>>(outh, gstart, Ssum, Ssq, galpha, gw, gb, Pmax);
  k_flat<<<NUM_G, 128, 0, stream>>>(Pmax, flat);
}

// Round 17
// 323.107 us; speedup vs baseline: 1.0628x; 1.0285x over previous
//
#include <hip/hip_runtime.h>
#include <math.h>

typedef float f4 __attribute__((ext_vector_type(4)));
typedef float f2 __attribute__((ext_vector_type(2)));

#define NUM_G 64
#define CH 16          // per-graph chunks for deterministic partial reductions
#define EPSV 1e-5f

__device__ inline f4 f4_max(f4 a, f4 b) {
  f4 r;
#pragma unroll
  for (int i = 0; i < 4; ++i) r[i] = fmaxf(a[i], b[i]);
  return r;
}

// bf16 round-to-nearest-even (values are finite, no NaN handling needed)
__device__ inline unsigned bf16rne(float f) {
  unsigned u = __float_as_uint(f);
  return (u + 0x7fffu + ((u >> 16) & 1u)) >> 16;
}

// ---------------- init: deg=1 (self loop), ecnt=0, graph start offsets ----------------
__global__ void k_init(const int* __restrict__ batch, float* __restrict__ deg,
                       int* __restrict__ ecnt, int* __restrict__ gstart, int N) {
  int n = blockIdx.x * blockDim.x + threadIdx.x;
  if (n >= N) return;
  deg[n] = 1.0f;
  ecnt[n] = 0;
  int bn = batch[n];
  int bp = (n == 0) ? -1 : batch[n - 1];
  for (int g = bp + 1; g <= bn; ++g) gstart[g] = n;
  if (n == N - 1) {
    for (int g = bn + 1; g <= NUM_G; ++g) gstart[g] = N;
  }
}

// ---------------- weighted in-degree + edge count histogram ----------------
__global__ void k_deg(const int* __restrict__ col, const float* __restrict__ ew,
                      float* __restrict__ deg, int* __restrict__ ecnt, int E) {
  int e = blockIdx.x * blockDim.x + threadIdx.x;
  if (e >= E) return;
  int c = col[e];
  atomicAdd(&deg[c], ew[e]);
  atomicAdd(&ecnt[c], 1);
}

// ---------------- two-level scan, phase A: per-block totals ----------------
__global__ __launch_bounds__(256) void k_scanA(const int* __restrict__ ecnt,
                                               int* __restrict__ bsum, int N) {
  __shared__ int sb[256];
  int n = blockIdx.x * 256 + threadIdx.x;
  sb[threadIdx.x] = (n < N) ? ecnt[n] : 0;
  __syncthreads();
  for (int o = 128; o >= 1; o >>= 1) {
    if (threadIdx.x < o) sb[threadIdx.x] += sb[threadIdx.x + o];
    __syncthreads();
  }
  if (threadIdx.x == 0) bsum[blockIdx.x] = sb[0];
}

// ---------------- phase B: scan the block sums (single small block) ----------------
__global__ __launch_bounds__(1024) void k_scanB(int* __restrict__ bsum,
                                                int* __restrict__ off, int NB, int N) {
  __shared__ int sb[1024];
  int t = threadIdx.x;
  int sc = (NB + 1023) >> 10;  // entries per thread (1 for NB<=1024)
  int s = t * sc, e = min(s + sc, NB);
  int local = 0;
  for (int i = s; i < e; ++i) local += bsum[i];
  sb[t] = local;
  __syncthreads();
  for (int o = 1; o < 1024; o <<= 1) {
    int v = sb[t];
    int a = (t >= o) ? sb[t - o] : 0;
    __syncthreads();
    sb[t] = v + a;
    __syncthreads();
  }
  int running = sb[t] - local;  // exclusive base for this thread's span
  for (int i = s; i < e; ++i) {
    int v = bsum[i];
    bsum[i] = running;
    running += v;
  }
  if (t == 0) off[N] = sb[1023];  // grand total
}

// ---------------- phase C: intra-block scan + base -> off/cursor; dis = rsqrt(deg) ----------------
__global__ __launch_bounds__(256) void k_scanC(const int* __restrict__ ecnt,
                                               const int* __restrict__ bsum,
                                               const float* __restrict__ deg,
                                               int* __restrict__ off, int* __restrict__ cursor,
                                               float* __restrict__ dis, int N) {
  __shared__ int sb[256];
  int n = blockIdx.x * 256 + threadIdx.x;
  int v = (n < N) ? ecnt[n] : 0;
  sb[threadIdx.x] = v;
  __syncthreads();
  for (int o = 1; o < 256; o <<= 1) {
    int x = sb[threadIdx.x];
    int a = (threadIdx.x >= o) ? sb[threadIdx.x - o] : 0;
    __syncthreads();
    sb[threadIdx.x] = x + a;
    __syncthreads();
  }
  if (n < N) {
    int ex = bsum[blockIdx.x] + sb[threadIdx.x] - v;  // exclusive prefix
    off[n] = ex;
    cursor[n] = ex;
    float d = deg[n];
    dis[n] = (d > 0.f) ? (1.0f / sqrtf(d)) : 0.f;
  }
}

// ---------------- GEMM: x = inputs @ W, both tiles LDS-staged; OUTPUT IN BF16 ----------------
// BM=64, BK=32, BN=128. 512 threads: lane=tid&31 -> 4 cols, rg=tid>>5 (0..15) -> 4 rows.
// x stored bf16 (RNE): halves x write traffic AND halves k_accum's per-edge gather bytes.
__global__ __launch_bounds__(512) void k_gemm(const float* __restrict__ in,
                                              const float* __restrict__ Wg,
                                              unsigned short* __restrict__ xb, int N) {
  __shared__ float As[64][32];   // 8 KiB
  __shared__ float Ws[32][128];  // 16 KiB
  int tid = threadIdx.x;
  int lane = tid & 31;   // cols 4*lane..4*lane+3
  int rg = tid >> 5;     // rows rg*4..rg*4+3
  int brow = blockIdx.x * 64;
  int ar = tid >> 3;         // 0..63: A stage row
  int aseg = (tid & 7) * 4;  // float offset within 32-float chunk
  const f4* wsrc0 = (const f4*)Wg;
  f4 acc0 = (f4)0.f, acc1 = (f4)0.f, acc2 = (f4)0.f, acc3 = (f4)0.f;
  for (int kc = 0; kc < 4; ++kc) {  // K chunks of 32, ascending (same summation order)
    int gr = brow + ar;
    f4 av = (f4)0.f;
    if (gr < N) av = *(const f4*)(in + (size_t)gr * 128 + kc * 32 + aseg);
    *(f4*)&As[ar][aseg] = av;
    const f4* wsrc = wsrc0 + (size_t)kc * 32 * 32;  // kc*32 rows, 32 f4 per row
    ((f4*)Ws)[tid] = wsrc[tid];
    ((f4*)Ws)[tid + 512] = wsrc[tid + 512];
    __syncthreads();
#pragma unroll
    for (int k4 = 0; k4 < 8; ++k4) {
      f4 a0 = *(const f4*)&As[rg * 4 + 0][k4 * 4];
      f4 a1 = *(const f4*)&As[rg * 4 + 1][k4 * 4];
      f4 a2 = *(const f4*)&As[rg * 4 + 2][k4 * 4];
      f4 a3 = *(const f4*)&As[rg * 4 + 3][k4 * 4];
#pragma unroll
      for (int kk = 0; kk < 4; ++kk) {
        f4 wv = *(const f4*)&Ws[k4 * 4 + kk][lane * 4];
        acc0 += a0[kk] * wv;
        acc1 += a1[kk] * wv;
        acc2 += a2[kk] * wv;
        acc3 += a3[kk] * wv;
      }
    }
    __syncthreads();
  }
  int r0 = brow + rg * 4;
#pragma unroll
  for (int rr = 0; rr < 4; ++rr) {
    if (r0 + rr >= N) break;
    f4 a = (rr == 0) ? acc0 : (rr == 1) ? acc1 : (rr == 2) ? acc2 : acc3;
    uint2 pk;
    pk.x = bf16rne(a[0]) | (bf16rne(a[1]) << 16);
    pk.y = bf16rne(a[2]) | (bf16rne(a[3]) << 16);
    ((uint2*)(xb + (size_t)(r0 + rr) * 128))[lane] = pk;  // 8B/lane, coalesced
  }
}

// ---------------- counting-sort scatter: build CSR-by-target, PACKED (r, norm) ----------------
__global__ void k_scatter(const int* __restrict__ row, const int* __restrict__ col,
                          const float* __restrict__ ew, const float* __restrict__ dis,
                          int* __restrict__ cursor, int2* __restrict__ sdata, int E) {
  int e = blockIdx.x * blockDim.x + threadIdx.x;
  if (e >= E) return;
  int r = row[e], c = col[e];
  float nm = dis[r] * ew[e] * dis[c];
  int p = atomicAdd(&cursor[c], 1);
  int2 pk;
  pk.x = r;
  pk.y = __float_as_int(nm);
  sdata[p] = pk;
}

// ---------------- per-node gather-accumulate: out = sum(msg) + selfloop + bias ----------------
// one node per 64-lane wave; x rows are bf16 (256B): lane reads one u32 = 2 feats.
// Unpack bf16 pair via shift<<16 (2 VALU ops) -> fp32 FMA into f2 accumulators.
__global__ __launch_bounds__(256) void k_accum(const unsigned short* __restrict__ xb,
                                               const float* __restrict__ dis,
                                               const int* __restrict__ off,
                                               const int2* __restrict__ sdata,
                                               const float* __restrict__ bias,
                                               float* __restrict__ out, int N) {
  int lane = threadIdx.x & 63;  // 64 lanes x u32 = 128 bf16 features
  int sub = threadIdx.x >> 6;   // 4 nodes per block
  int n = blockIdx.x * 4 + sub;
  if (n >= N) return;
  const unsigned* x32 = (const unsigned*)xb;
  float dn = dis[n];
  unsigned us = x32[(size_t)n * 64 + lane];
  f2 vs;
  vs.x = __uint_as_float((us & 0xffffu) << 16);
  vs.y = __uint_as_float((us >> 16) << 16);
  f2 acc0 = vs * (dn * dn);  // self-loop: norm = dis[n]^2
  f2 acc1 = (f2)0.f, acc2 = (f2)0.f, acc3 = (f2)0.f;
  int s = off[n], e = off[n + 1];
  int i = s;
  for (; i + 4 <= e; i += 4) {  // 4-deep MLP on the random row gathers
    int2 p0 = sdata[i], p1 = sdata[i + 1], p2 = sdata[i + 2], p3 = sdata[i + 3];
    unsigned u0 = x32[(size_t)p0.x * 64 + lane];
    unsigned u1 = x32[(size_t)p1.x * 64 + lane];
    unsigned u2 = x32[(size_t)p2.x * 64 + lane];
    unsigned u3 = x32[(size_t)p3.x * 64 + lane];
    f2 v0, v1, v2, v3;
    v0.x = __uint_as_float((u0 & 0xffffu) << 16); v0.y = __uint_as_float((u0 >> 16) << 16);
    v1.x = __uint_as_float((u1 & 0xffffu) << 16); v1.y = __uint_as_float((u1 >> 16) << 16);
    v2.x = __uint_as_float((u2 & 0xffffu) << 16); v2.y = __uint_as_float((u2 >> 16) << 16);
    v3.x = __uint_as_float((u3 & 0xffffu) << 16); v3.y = __uint_as_float((u3 >> 16) << 16);
    acc0 += v0 * __int_as_float(p0.y);
    acc1 += v1 * __int_as_float(p1.y);
    acc2 += v2 * __int_as_float(p2.y);
    acc3 += v3 * __int_as_float(p3.y);
  }
  for (; i < e; ++i) {
    int2 p = sdata[i];
    unsigned u = x32[(size_t)p.x * 64 + lane];
    f2 v;
    v.x = __uint_as_float((u & 0xffffu) << 16);
    v.y = __uint_as_float((u >> 16) << 16);
    acc0 += v * __int_as_float(p.y);
  }
  acc0 += (acc1 + acc2) + (acc3 + ((const f2*)bias)[lane]);
  ((f2*)out)[(size_t)n * 64 + lane] = acc0;
}

// ---------------- GraphNorm fused stats: partial sum AND sum-of-squares per (graph, chunk) ----------------
__global__ __launch_bounds__(256) void k_stats(const float* __restrict__ out,
                                               const int* __restrict__ gstart,
                                               float* __restrict__ Ssum,
                                               float* __restrict__ Ssq) {
  int g = blockIdx.x / CH, c = blockIdx.x % CH;
  int s = gstart[g], e = gstart[g + 1];
  int len = e - s;
  int csz = (len + CH - 1) / CH;
  int r0 = s + c * csz, r1 = min(r0 + csz, e);
  int lane = threadIdx.x & 31, rg = threadIdx.x >> 5;
  const f4* out4 = (const f4*)out;
  f4 acc = (f4)0.f, accq = (f4)0.f;
  for (int r = r0 + rg; r < r1; r += 8) {
    f4 v = out4[(size_t)r * 32 + lane];
    acc += v;
    accq += v * v;
  }
  __shared__ f4 red[256], redq[256];
  red[threadIdx.x] = acc;
  redq[threadIdx.x] = accq;
  __syncthreads();
  for (int st = 4; st >= 1; st >>= 1) {
    if (rg < st) {
      red[threadIdx.x] += red[threadIdx.x + st * 32];
      redq[threadIdx.x] += redq[threadIdx.x + st * 32];
    }
    __syncthreads();
  }
  if (rg == 0) {
    ((f4*)Ssum)[(size_t)(g * CH + c) * 32 + lane] = red[threadIdx.x];
    ((f4*)Ssq)[(size_t)(g * CH + c) * 32 + lane] = redq[threadIdx.x];
  }
}

// ---------------- finalize: h = relu((out-alpha*mean)*invstd*w + b); partial max ----------------
// var = E[(out-am)^2] = E[out^2] - 2*am*E[out] + am^2, am = alpha*mean
__global__ __launch_bounds__(256) void k_final(float* __restrict__ out,
                                               const int* __restrict__ gstart,
                                               const float* __restrict__ Ssum,
                                               const float* __restrict__ Ssq,
                                               const float* __restrict__ alpha,
                                               const float* __restrict__ gw,
                                               const float* __restrict__ gb,
                                               float* __restrict__ Pmax) {
  int g = blockIdx.x / CH, c = blockIdx.x % CH;
  int s = gstart[g], e = gstart[g + 1];
  int len = e - s;
  float inv_cnt = 1.0f / (float)((len < 1) ? 1 : len);
  __shared__ f4 aml[32], istdl[32];
  int lane = threadIdx.x & 31, rg = threadIdx.x >> 5;
  if (threadIdx.x < 32) {
    f4 m = (f4)0.f, q = (f4)0.f;
    for (int cc = 0; cc < CH; ++cc) {
      m += ((const f4*)Ssum)[(size_t)(g * CH + cc) * 32 + threadIdx.x];
      q += ((const f4*)Ssq)[(size_t)(g * CH + cc) * 32 + threadIdx.x];
    }
    m *= inv_cnt;                                 // E[out]
    q *= inv_cnt;                                 // E[out^2]
    f4 al = ((const f4*)alpha)[threadIdx.x];
    f4 am = al * m;
    f4 var = q - 2.0f * am * m + am * am;         // E[(out-am)^2]
    f4 is;
#pragma unroll
    for (int i = 0; i < 4; ++i) is[i] = 1.0f / sqrtf(var[i] + EPSV);
    aml[threadIdx.x] = am;
    istdl[threadIdx.x] = is;
  }
  __syncthreads();
  int csz = (len + CH - 1) / CH;
  int r0 = s + c * csz, r1 = min(r0 + csz, e);
  f4 am = aml[lane];
  f4 is = istdl[lane];
  f4 w4 = ((const f4*)gw)[lane];
  f4 b4 = ((const f4*)gb)[lane];
  f4* out4 = (f4*)out;
  f4 mx = (f4)0.f;  // relu output >= 0, so 0 is a safe identity
  for (int r = r0 + rg; r < r1; r += 8) {
    f4 o = out4[(size_t)r * 32 + lane];
    f4 h = (o - am) * is * w4 + b4;
    h = f4_max(h, (f4)0.f);
    out4[(size_t)r * 32 + lane] = h;
    mx = f4_max(mx, h);
  }
  __shared__ f4 red[256];
  red[threadIdx.x] = mx;
  __syncthreads();
  for (int st = 4; st >= 1; st >>= 1) {
    if (rg < st) red[threadIdx.x] = f4_max(red[threadIdx.x], red[threadIdx.x + st * 32]);
    __syncthreads();
  }
  if (rg == 0) ((f4*)Pmax)[(size_t)(g * CH + c) * 32 + lane] = red[threadIdx.x];
}

// ---------------- combine partial maxes -> flat ----------------
__global__ void k_flat(const float* __restrict__ Pmax, float* __restrict__ flat) {
  int g = blockIdx.x;
  int f = threadIdx.x;  // 128 threads
  float m = 0.f;
  for (int c = 0; c < CH; ++c) m = fmaxf(m, Pmax[((size_t)g * CH + c) * 128 + f]);
  flat[g * 128 + f] = m;
}

extern "C" void kernel_launch(void* const* d_in, const int* in_sizes, int n_in,
                              void* d_out, int out_size, void* d_ws, size_t ws_size,
                              hipStream_t stream) {
  const float* inputs = (const float*)d_in[0];
  const int* eidx = (const int*)d_in[1];
  const int* batch = (const int*)d_in[2];
  const float* ew = (const float*)d_in[3];
  const float* Wg = (const float*)d_in[4];
  const float* bias = (const float*)d_in[5];
  const float* gw = (const float*)d_in[6];
  const float* gb = (const float*)d_in[7];
  const float* galpha = (const float*)d_in[8];

  int N = in_sizes[0] / 128;
  int E = in_sizes[1] / 2;
  const int* erow = eidx;       // edge_index[0] = source
  const int* ecol = eidx + E;   // edge_index[1] = target

  char* w = (char*)d_ws;
  auto alloc = [&](size_t bytes) {
    char* p = w;
    w += (bytes + 255) & ~(size_t)255;
    return p;
  };
  unsigned short* xb = (unsigned short*)alloc((size_t)N * 128 * 2);  // bf16 x
  float* deg = (float*)alloc((size_t)N * 4);
  float* dis = (float*)alloc((size_t)N * 4);
  int* ecnt = (int*)alloc((size_t)N * 4);
  int* off = (int*)alloc((size_t)(N + 1) * 4);
  int* cursor = (int*)alloc((size_t)N * 4);
  int2* sdata = (int2*)alloc((size_t)E * 8);
  int* gstart = (int*)alloc((size_t)(NUM_G + 1) * 4);
  float* Ssum = (float*)alloc((size_t)NUM_G * CH * 128 * 4);
  float* Ssq = (float*)alloc((size_t)NUM_G * CH * 128 * 4);
  float* Pmax = (float*)alloc((size_t)NUM_G * CH * 128 * 4);
  int NB = (N + 255) / 256;
  int* bsum = (int*)alloc((size_t)NB * 4);

  float* outh = (float*)d_out;             // h: N x 128
  float* flat = outh + (size_t)N * 128;    // flat: 64 x 128

  k_init<<<(N + 255) / 256, 256, 0, stream>>>(batch, deg, ecnt, gstart, N);
  k_deg<<<(E + 255) / 256, 256, 0, stream>>>(ecol, ew, deg, ecnt, E);
  k_scanA<<<NB, 256, 0, stream>>>(ecnt, bsum, N);
  k_scanB<<<1, 1024, 0, stream>>>(bsum, off, NB, N);
  k_scanC<<<NB, 256, 0, stream>>>(ecnt, bsum, deg, off, cursor, dis, N);
  k_gemm<<<(N + 63) / 64, 512, 0, stream>>>(inputs, Wg, xb, N);
  k_scatter<<<(E + 255) / 256, 256, 0, stream>>>(erow, ecol, ew, dis, cursor, sdata, E);
  k_accum<<<(N + 3) / 4, 256, 0, stream>>>(xb, dis, off, sdata, bias, outh, N);
  k_stats<<<NUM_G * CH, 256, 0, stream>>>(outh, gstart, Ssum, Ssq);
  k_final<<<NUM_G * CH, 256, 0, stream>>>(outh, gstart, Ssum, Ssq, galpha, gw, gb, Pmax);
  k_flat<<<NUM_G, 128, 0, stream>>>(Pmax, flat);
}